// Round 7
// baseline (120.085 us; speedup 1.0000x reference)
//
#include <hip/hip_runtime.h>
#include <math.h>

#define CCH 256
#define HW  9216
#define CW  24576
#define TWO_PI 6.28318530717958647692f

typedef __attribute__((ext_vector_type(8))) short short8;
typedef __attribute__((ext_vector_type(4))) float f32x4;

__device__ inline unsigned short f2bf(float f) {
    unsigned u = __float_as_uint(f);
    unsigned r = (u + 0x7FFFu + ((u >> 16) & 1u)) >> 16;   // RNE
    return (unsigned short)r;
}

// ---------------- K_wf: weights -> bf16 tiles [ot][kc][m]; zero FQm ----------------
__global__ __launch_bounds__(256) void k_wf(const float* __restrict__ Wq,
                                            const float* __restrict__ Wv,
                                            short8* __restrict__ Wqt,
                                            short8* __restrict__ Wvt,
                                            unsigned* __restrict__ FQm) {
    int widx = blockIdx.x;                        // 0..63
    int t = threadIdx.x;
    int z0 = widx * 384;
    FQm[z0 + t] = 0u;
    if (t < 128) FQm[z0 + 256 + t] = 0u;
    const float* src = (widx >= 32) ? Wv : Wq;
    short8* dst = (widx >= 32) ? Wvt : Wqt;
    int cidx = (widx & 31) * 256 + t;             // 0..8191
    int ot = cidx >> 11, kc = (cidx >> 6) & 31, m = cidx & 63;
    const float* s = src + (ot * 64 + m) * 256 + kc * 8;
    short8 v;
    #pragma unroll
    for (int e = 0; e < 8; ++e) v[e] = (short)f2bf(s[e]);
    dst[cidx] = v;
}

// ---------------- K_dft: self-contained minmax + 16 DFT coefficients per channel ----------------
// Kept freqs (un-fftshifted): ky,kx in {-2,-1,0,1}. Writes Fg[c*32 + 2*(ky*4+kx) + {re,im}].
__global__ __launch_bounds__(768) void k_dft(const float* __restrict__ x,
                                             float* __restrict__ Fg) {
    __shared__ float qa[HW];         // 36 KB |x|
    __shared__ float cs[96][2];
    __shared__ float Gp[8][96][5];
    __shared__ float Gs[96][6];
    __shared__ float red[24];
    __shared__ float s_mn, s_ptp;
    int c = blockIdx.x, t = threadIdx.x;
    const float* xp = x + c * HW;
    if (t < 96) { float a = TWO_PI * (float)t / 96.0f; cs[t][0] = cosf(a); cs[t][1] = sinf(a); }
    float lo = 1e30f, hi = 0.f;
    #pragma unroll
    for (int i = 0; i < 12; ++i) {
        float a = fabsf(xp[t + i * 768]);
        qa[t + i * 768] = a;
        lo = fminf(lo, a);
        hi = fmaxf(hi, a);
    }
    #pragma unroll
    for (int d = 32; d; d >>= 1) {
        lo = fminf(lo, __shfl_xor(lo, d, 64));
        hi = fmaxf(hi, __shfl_xor(hi, d, 64));
    }
    if ((t & 63) == 0) { red[t >> 6] = lo; red[12 + (t >> 6)] = hi; }
    __syncthreads();
    if (t == 0) {
        lo = red[0]; hi = red[12];
        #pragma unroll
        for (int i = 1; i < 12; ++i) { lo = fminf(lo, red[i]); hi = fmaxf(hi, red[12 + i]); }
        s_mn = lo; s_ptp = hi - lo;
    }
    __syncthreads();
    float mn = s_mn, ptp = s_ptp;

    // Phase A: thread (xx = t%96, h = t/96) sums 12 rows of the column DFT from LDS
    {
        int xx = t % 96, h = t / 96;
        float g0r = 0, g0i = 0, g1r = 0, g1i = 0, g2 = 0;
        for (int y = h * 12; y < h * 12 + 12; ++y) {
            float q = floorf(255.0f * (qa[y * 96 + xx] - mn) / ptp);
            float c1 = cs[y][0], s1 = cs[y][1];
            float c2 = c1 * c1 - s1 * s1, s2 = 2.0f * c1 * s1;
            g0r += q * c2; g0i += q * s2;   // k=-2: e^{+2iθ}
            g1r += q * c1; g1i += q * s1;   // k=-1: e^{+iθ}
            g2  += q;                       // k=0
        }
        Gp[h][xx][0] = g0r; Gp[h][xx][1] = g0i;
        Gp[h][xx][2] = g1r; Gp[h][xx][3] = g1i;
        Gp[h][xx][4] = g2;
    }
    __syncthreads();
    if (t < 96) {
        #pragma unroll
        for (int j = 0; j < 5; ++j) {
            float s = 0.f;
            #pragma unroll
            for (int h = 0; h < 8; ++h) s += Gp[h][t][j];
            Gs[t][j] = s;
        }
        Gs[t][5] = 0.f;
    }
    __syncthreads();
    if (t < 64) {
        int coef = t >> 2, qq = t & 3;
        int ky = coef >> 2, kx = coef & 3;
        float fr = 0, fi = 0;
        for (int xx = qq * 24; xx < qq * 24 + 24; ++xx) {
            float c1 = cs[xx][0], s1 = cs[xx][1];
            float er, ei;
            if (kx == 0)      { er = c1 * c1 - s1 * s1; ei = 2.0f * c1 * s1; }
            else if (kx == 1) { er = c1; ei = s1; }
            else if (kx == 2) { er = 1.f; ei = 0.f; }
            else              { er = c1; ei = -s1; }
            float gr, gi;
            if (ky == 0)      { gr = Gs[xx][0]; gi = Gs[xx][1]; }
            else if (ky == 1) { gr = Gs[xx][2]; gi = Gs[xx][3]; }
            else if (ky == 2) { gr = Gs[xx][4]; gi = 0.f; }
            else              { gr = Gs[xx][2]; gi = -Gs[xx][3]; }
            fr += gr * er - gi * ei;
            fi += gr * ei + gi * er;
        }
        fr += __shfl_xor(fr, 1, 64); fr += __shfl_xor(fr, 2, 64);
        fi += __shfl_xor(fi, 1, 64); fi += __shfl_xor(fi, 2, 64);
        if (qq == 0) {
            Fg[c * 32 + 2 * coef]     = fr;
            Fg[c * 32 + 2 * coef + 1] = fi;
        }
    }
}

// ---------------- GEMM1: Q = Wq*FQ, B synthesized in-LDS; epilogue = column-max ----------------
__global__ __launch_bounds__(256) void k_gemm1(const short8* __restrict__ Wt,
                                               const float* __restrict__ Fg,
                                               const float* __restrict__ bias,
                                               unsigned* __restrict__ FQm) {
    __shared__ short8 As[2048];     // 32 KB [kc][m]
    __shared__ short8 Bs[2048];     // 32 KB [kc][n]
    __shared__ float Rs[2048][2];   // 16 KB [c*8 + yi*4 + kx]
    int tid = threadIdx.x;
    int pt_ = blockIdx.x, ot = blockIdx.y;
    const short8* wsrc = Wt + ot * 2048;
    #pragma unroll
    for (int i = 0; i < 8; ++i) As[i * 256 + tid] = wsrc[i * 256 + tid];

    int p0 = pt_ * 64;
    int y0 = p0 / 96;
    // R[c][yi][kx] = sum_ky F[c][ky][kx] * U[ky](y0+yi)
    {
        int yi = (tid >> 2) & 1, kx = tid & 3, cb = tid >> 3;
        float ay = TWO_PI * (float)(y0 + yi) / 96.0f;
        float cyv = cosf(ay), syv = sinf(ay);
        float cy2 = cyv * cyv - syv * syv, sy2 = 2.f * cyv * syv;
        float Ur[4] = { cy2, cyv, 1.f, cyv };
        float Ui[4] = { -sy2, -syv, 0.f, syv };
        #pragma unroll
        for (int i = 0; i < 8; ++i) {
            int cc = cb + i * 32;
            float rr = 0.f, ri = 0.f;
            #pragma unroll
            for (int ky = 0; ky < 4; ++ky) {
                float fr = Fg[cc * 32 + 2 * (ky * 4 + kx)];
                float fi = Fg[cc * 32 + 2 * (ky * 4 + kx) + 1];
                rr += fr * Ur[ky] - fi * Ui[ky];
                ri += fr * Ui[ky] + fi * Ur[ky];
            }
            Rs[cc * 8 + yi * 4 + kx][0] = rr;
            Rs[cc * 8 + yi * 4 + kx][1] = ri;
        }
    }
    __syncthreads();
    // Bs[kc][n] = f2bf(|sum_kx R[c][yi(n)][kx] * T[kx](x(n))| / 9216)
    const float inv = 1.0f / 9216.0f;
    #pragma unroll
    for (int i = 0; i < 8; ++i) {
        int si = i * 256 + tid;
        int kcg = si >> 6, n = si & 63;
        int p = p0 + n;
        int y = p / 96, xx = p - y * 96;
        int yi = y - y0;
        float axv = TWO_PI * (float)xx / 96.0f;
        float cxv = cosf(axv), sxv = sinf(axv);
        float cx2 = cxv * cxv - sxv * sxv, sx2 = 2.f * cxv * sxv;
        float Tr[4] = { cx2, cxv, 1.f, cxv };
        float Ti[4] = { -sx2, -sxv, 0.f, sxv };
        short8 vv;
        #pragma unroll
        for (int e = 0; e < 8; ++e) {
            int rb = (kcg * 8 + e) * 8 + yi * 4;
            float ar = 0.f, ai = 0.f;
            #pragma unroll
            for (int kx = 0; kx < 4; ++kx) {
                float rr = Rs[rb + kx][0], ri = Rs[rb + kx][1];
                ar += rr * Tr[kx] - ri * Ti[kx];
                ai += rr * Ti[kx] + ri * Tr[kx];
            }
            vv[e] = (short)f2bf(sqrtf(ar * ar + ai * ai) * inv);
        }
        Bs[si] = vv;
    }
    __syncthreads();

    int l = tid & 63, w = tid >> 6;
    int wr = w >> 1, wc = w & 1;
    int l15 = l & 15, quad = l >> 4;
    f32x4 acc[2][2] = {};
    int abase = wr * 32 + l15;
    int bbase = wc * 32 + l15;
    #pragma unroll
    for (int s = 0; s < 8; ++s) {
        int kc = s * 4 + quad;
        short8 a0 = As[kc * 64 + abase];
        short8 a1 = As[kc * 64 + abase + 16];
        short8 b0 = Bs[kc * 64 + bbase];
        short8 b1 = Bs[kc * 64 + bbase + 16];
        acc[0][0] = __builtin_amdgcn_mfma_f32_16x16x32_bf16(a0, b0, acc[0][0], 0, 0, 0);
        acc[0][1] = __builtin_amdgcn_mfma_f32_16x16x32_bf16(a0, b1, acc[0][1], 0, 0, 0);
        acc[1][0] = __builtin_amdgcn_mfma_f32_16x16x32_bf16(a1, b0, acc[1][0], 0, 0, 0);
        acc[1][1] = __builtin_amdgcn_mfma_f32_16x16x32_bf16(a1, b1, acc[1][1], 0, 0, 0);
    }
    // C/D layout: col = lane&15, row = quad*4 + reg
    #pragma unroll
    for (int ni = 0; ni < 2; ++ni) {
        #pragma unroll
        for (int r = 0; r < 4; ++r) {
            int o_lo = ot * 64 + wr * 32 + quad * 4 + r;
            float v = fmaxf(acc[0][ni][r] + bias[o_lo], acc[1][ni][r] + bias[o_lo + 16]);
            v = fmaxf(v, __shfl_xor(v, 32, 64));
            if (quad < 2) {
                int p = pt_ * 64 + wc * 32 + ni * 16 + l15;
                int k = ((quad * 4 + r) & 7) * HW + p;
                if (k >= CW) k -= CW;
                if (k >= CW) k -= CW;
                unsigned u = __float_as_uint(v);
                unsigned key = (u & 0x80000000u) ? ~u : (u | 0x80000000u);
                atomicMax(&FQm[k], key);
            }
        }
    }
}

// ---------------- GEMM2: V = Wv*fuse, B transposed in-block; epilogue = mask ----------------
__global__ __launch_bounds__(256) void k_gemm2(const short8* __restrict__ Wt,
                                               const float* __restrict__ x,
                                               const float* __restrict__ bias,
                                               const unsigned* __restrict__ FQm,
                                               float* __restrict__ out) {
    __shared__ short8 As[2048];          // 32 KB
    __shared__ short8 Bs[2048];          // 32 KB
    __shared__ unsigned short lt[64][66];// 8.25 KB
    int tid = threadIdx.x;
    int pt_ = blockIdx.x, ot = blockIdx.y;
    const short8* wsrc = Wt + ot * 2048;
    #pragma unroll
    for (int i = 0; i < 8; ++i) As[i * 256 + tid] = wsrc[i * 256 + tid];

    int p0 = pt_ * 64;
    int tx = tid & 63, tw = tid >> 6;
    for (int ct4 = 0; ct4 < 4; ++ct4) {
        #pragma unroll
        for (int i = 0; i < 16; ++i) {
            int row = tw * 16 + i;
            lt[row][tx] = f2bf(x[(size_t)(ct4 * 64 + row) * HW + p0 + tx]);
        }
        __syncthreads();
        #pragma unroll
        for (int ch = 0; ch < 2; ++ch) {
            int lc = ch * 256 + tid;
            int kcg = lc >> 6, n = lc & 63;
            short8 v;
            #pragma unroll
            for (int e = 0; e < 8; ++e) v[e] = (short)lt[kcg * 8 + e][n];
            Bs[(ct4 * 8 + kcg) * 64 + n] = v;
        }
        __syncthreads();
    }

    int l = tid & 63, w = tid >> 6;
    int wr = w >> 1, wc = w & 1;
    int l15 = l & 15, quad = l >> 4;
    f32x4 acc[2][2] = {};
    int abase = wr * 32 + l15;
    int bbase = wc * 32 + l15;
    #pragma unroll
    for (int s = 0; s < 8; ++s) {
        int kc = s * 4 + quad;
        short8 a0 = As[kc * 64 + abase];
        short8 a1 = As[kc * 64 + abase + 16];
        short8 b0 = Bs[kc * 64 + bbase];
        short8 b1 = Bs[kc * 64 + bbase + 16];
        acc[0][0] = __builtin_amdgcn_mfma_f32_16x16x32_bf16(a0, b0, acc[0][0], 0, 0, 0);
        acc[0][1] = __builtin_amdgcn_mfma_f32_16x16x32_bf16(a0, b1, acc[0][1], 0, 0, 0);
        acc[1][0] = __builtin_amdgcn_mfma_f32_16x16x32_bf16(a1, b0, acc[1][0], 0, 0, 0);
        acc[1][1] = __builtin_amdgcn_mfma_f32_16x16x32_bf16(a1, b1, acc[1][1], 0, 0, 0);
    }
    #pragma unroll
    for (int mi = 0; mi < 2; ++mi) {
        #pragma unroll
        for (int ni = 0; ni < 2; ++ni) {
            #pragma unroll
            for (int r = 0; r < 4; ++r) {
                int o = ot * 64 + wr * 32 + mi * 16 + quad * 4 + r;
                int p = pt_ * 64 + wc * 32 + ni * 16 + l15;
                int k = ((quad * 4 + r) & 7) * HW + p;
                if (k >= CW) k -= CW;
                if (k >= CW) k -= CW;
                unsigned key = FQm[k];
                unsigned ub = (key & 0x80000000u) ? (key ^ 0x80000000u) : ~key;
                float m = __uint_as_float(ub);
                float v = acc[mi][ni][r] + bias[o];
                out[(size_t)o * HW + p] = v * (1.0f + m);
            }
        }
    }
}

extern "C" void kernel_launch(void* const* d_in, const int* in_sizes, int n_in,
                              void* d_out, int out_size, void* d_ws, size_t ws_size,
                              hipStream_t stream) {
    const float* fuse = (const float*)d_in[0];
    const float* Wq   = (const float*)d_in[1];
    const float* bq   = (const float*)d_in[2];
    // d_in[3]=Wk, d_in[4]=bk dead for B=1 (softmax over batch axis of size 1 == 1)
    const float* Wv   = (const float*)d_in[5];
    const float* bv   = (const float*)d_in[6];
    float* out = (float*)d_out;

    char* ws = (char*)d_ws;
    unsigned* FQm = (unsigned*)(ws);            //  98304 B (zeroed by k_wf)
    float*    Fg  = (float*)(ws + 98304);       //  32768 B
    short8*   Wqt = (short8*)(ws + 131072);     // 131072 B
    short8*   Wvt = (short8*)(ws + 262144);     // 131072 B

    k_wf<<<64, 256, 0, stream>>>(Wq, Wv, Wqt, Wvt, FQm);
    k_dft<<<256, 768, 0, stream>>>(fuse, Fg);
    k_gemm1<<<dim3(144, 4), 256, 0, stream>>>(Wqt, Fg, bq, FQm);
    k_gemm2<<<dim3(144, 4), 256, 0, stream>>>(Wvt, fuse, bv, FQm, out);
}

// Round 8
// 115.558 us; speedup vs baseline: 1.0392x; 1.0392x over previous
//
#include <hip/hip_runtime.h>
#include <math.h>

#define CCH 256
#define HW  9216
#define CW  24576
#define TWO_PI 6.28318530717958647692f

typedef __attribute__((ext_vector_type(8))) short short8;
typedef __attribute__((ext_vector_type(4))) float f32x4;

__device__ inline unsigned short f2bf(float f) {
    unsigned u = __float_as_uint(f);
    unsigned r = (u + 0x7FFFu + ((u >> 16) & 1u)) >> 16;   // RNE
    return (unsigned short)r;
}

// ---------------- K_pre: fused {per-channel DFT + FQm zero} and {weight conversion} ----------------
// blocks [0,256):  channel c = bid: |x| minmax + 16 DFT coefficients -> Fg; zero FQm slice
// blocks [256,320): Wq/Wv -> bf16 tiles [ot][kc][m]
__global__ __launch_bounds__(768) void k_pre(const float* __restrict__ x,
                                             const float* __restrict__ Wq,
                                             const float* __restrict__ Wv,
                                             short8* __restrict__ Wqt,
                                             short8* __restrict__ Wvt,
                                             unsigned* __restrict__ FQm,
                                             float* __restrict__ Fg) {
    __shared__ float qa[HW];         // 36 KB |x|
    __shared__ float cs[96][2];
    __shared__ float Gp[8][96][5];
    __shared__ float Gs[96][6];
    __shared__ float red[24];
    __shared__ float s_mn, s_ptp;
    int bid = blockIdx.x, t = threadIdx.x;

    if (bid >= 256) {                // weight-conversion blocks
        int widx = bid - 256;        // 0..63
        if (t < 256) {
            const float* src = (widx >= 32) ? Wv : Wq;
            short8* dst = (widx >= 32) ? Wvt : Wqt;
            int cidx = (widx & 31) * 256 + t;             // 0..8191
            int ot = cidx >> 11, kc = (cidx >> 6) & 31, m = cidx & 63;
            const float* s = src + (ot * 64 + m) * 256 + kc * 8;
            short8 v;
            #pragma unroll
            for (int e = 0; e < 8; ++e) v[e] = (short)f2bf(s[e]);
            dst[cidx] = v;
        }
        return;
    }

    int c = bid;
    if (t < 96) FQm[c * 96 + t] = 0u;   // zero FQm (24576 words over 256 blocks)
    const float* xp = x + c * HW;
    if (t < 96) { float a = TWO_PI * (float)t / 96.0f; cs[t][0] = cosf(a); cs[t][1] = sinf(a); }
    float lo = 1e30f, hi = 0.f;
    #pragma unroll
    for (int i = 0; i < 12; ++i) {
        float a = fabsf(xp[t + i * 768]);
        qa[t + i * 768] = a;
        lo = fminf(lo, a);
        hi = fmaxf(hi, a);
    }
    #pragma unroll
    for (int d = 32; d; d >>= 1) {
        lo = fminf(lo, __shfl_xor(lo, d, 64));
        hi = fmaxf(hi, __shfl_xor(hi, d, 64));
    }
    if ((t & 63) == 0) { red[t >> 6] = lo; red[12 + (t >> 6)] = hi; }
    __syncthreads();
    if (t == 0) {
        lo = red[0]; hi = red[12];
        #pragma unroll
        for (int i = 1; i < 12; ++i) { lo = fminf(lo, red[i]); hi = fmaxf(hi, red[12 + i]); }
        s_mn = lo; s_ptp = hi - lo;
    }
    __syncthreads();
    float mn = s_mn, ptp = s_ptp;

    // Phase A: thread (xx = t%96, h = t/96) sums 12 rows of the column DFT from LDS
    {
        int xx = t % 96, h = t / 96;
        float g0r = 0, g0i = 0, g1r = 0, g1i = 0, g2 = 0;
        for (int y = h * 12; y < h * 12 + 12; ++y) {
            float q = floorf(255.0f * (qa[y * 96 + xx] - mn) / ptp);
            float c1 = cs[y][0], s1 = cs[y][1];
            float c2 = c1 * c1 - s1 * s1, s2 = 2.0f * c1 * s1;
            g0r += q * c2; g0i += q * s2;   // k=-2: e^{+2iθ}
            g1r += q * c1; g1i += q * s1;   // k=-1: e^{+iθ}
            g2  += q;                       // k=0
        }
        Gp[h][xx][0] = g0r; Gp[h][xx][1] = g0i;
        Gp[h][xx][2] = g1r; Gp[h][xx][3] = g1i;
        Gp[h][xx][4] = g2;
    }
    __syncthreads();
    if (t < 96) {
        #pragma unroll
        for (int j = 0; j < 5; ++j) {
            float s = 0.f;
            #pragma unroll
            for (int h = 0; h < 8; ++h) s += Gp[h][t][j];
            Gs[t][j] = s;
        }
        Gs[t][5] = 0.f;
    }
    __syncthreads();
    if (t < 64) {
        int coef = t >> 2, qq = t & 3;
        int ky = coef >> 2, kx = coef & 3;
        float fr = 0, fi = 0;
        for (int xx = qq * 24; xx < qq * 24 + 24; ++xx) {
            float c1 = cs[xx][0], s1 = cs[xx][1];
            float er, ei;
            if (kx == 0)      { er = c1 * c1 - s1 * s1; ei = 2.0f * c1 * s1; }
            else if (kx == 1) { er = c1; ei = s1; }
            else if (kx == 2) { er = 1.f; ei = 0.f; }
            else              { er = c1; ei = -s1; }
            float gr, gi;
            if (ky == 0)      { gr = Gs[xx][0]; gi = Gs[xx][1]; }
            else if (ky == 1) { gr = Gs[xx][2]; gi = Gs[xx][3]; }
            else if (ky == 2) { gr = Gs[xx][4]; gi = 0.f; }
            else              { gr = Gs[xx][2]; gi = -Gs[xx][3]; }
            fr += gr * er - gi * ei;
            fi += gr * ei + gi * er;
        }
        fr += __shfl_xor(fr, 1, 64); fr += __shfl_xor(fr, 2, 64);
        fi += __shfl_xor(fi, 1, 64); fi += __shfl_xor(fi, 2, 64);
        if (qq == 0) {
            Fg[c * 32 + 2 * coef]     = fr;
            Fg[c * 32 + 2 * coef + 1] = fi;
        }
    }
}

// ---------------- GEMM1: Q = Wq*FQ, B synthesized in-LDS; epilogue = column-max ----------------
__global__ __launch_bounds__(256) void k_gemm1(const short8* __restrict__ Wt,
                                               const float* __restrict__ Fg,
                                               const float* __restrict__ bias,
                                               unsigned* __restrict__ FQm) {
    __shared__ short8 As[2048];     // 32 KB [kc][m]
    __shared__ short8 Bs[2048];     // 32 KB [kc][n]
    __shared__ float Rs[2048][2];   // 16 KB [c*8 + yi*4 + kx]
    int tid = threadIdx.x;
    int pt_ = blockIdx.x, ot = blockIdx.y;
    const short8* wsrc = Wt + ot * 2048;
    #pragma unroll
    for (int i = 0; i < 8; ++i) As[i * 256 + tid] = wsrc[i * 256 + tid];

    int p0 = pt_ * 64;
    int y0 = p0 / 96;
    // R[c][yi][kx] = sum_ky F[c][ky][kx] * U[ky](y0+yi)
    {
        int yi = (tid >> 2) & 1, kx = tid & 3, cb = tid >> 3;
        float ay = TWO_PI * (float)(y0 + yi) / 96.0f;
        float cyv = cosf(ay), syv = sinf(ay);
        float cy2 = cyv * cyv - syv * syv, sy2 = 2.f * cyv * syv;
        float Ur[4] = { cy2, cyv, 1.f, cyv };
        float Ui[4] = { -sy2, -syv, 0.f, syv };
        #pragma unroll
        for (int i = 0; i < 8; ++i) {
            int cc = cb + i * 32;
            float rr = 0.f, ri = 0.f;
            #pragma unroll
            for (int ky = 0; ky < 4; ++ky) {
                float fr = Fg[cc * 32 + 2 * (ky * 4 + kx)];
                float fi = Fg[cc * 32 + 2 * (ky * 4 + kx) + 1];
                rr += fr * Ur[ky] - fi * Ui[ky];
                ri += fr * Ui[ky] + fi * Ur[ky];
            }
            Rs[cc * 8 + yi * 4 + kx][0] = rr;
            Rs[cc * 8 + yi * 4 + kx][1] = ri;
        }
    }
    __syncthreads();
    // Bs[kc][n] = f2bf(|sum_kx R[c][yi(n)][kx] * T[kx](x(n))| / 9216)
    const float inv = 1.0f / 9216.0f;
    #pragma unroll
    for (int i = 0; i < 8; ++i) {
        int si = i * 256 + tid;
        int kcg = si >> 6, n = si & 63;
        int p = p0 + n;
        int y = p / 96, xx = p - y * 96;
        int yi = y - y0;
        float axv = TWO_PI * (float)xx / 96.0f;
        float cxv = cosf(axv), sxv = sinf(axv);
        float cx2 = cxv * cxv - sxv * sxv, sx2 = 2.f * cxv * sxv;
        float Tr[4] = { cx2, cxv, 1.f, cxv };
        float Ti[4] = { -sx2, -sxv, 0.f, sxv };
        short8 vv;
        #pragma unroll
        for (int e = 0; e < 8; ++e) {
            int rb = (kcg * 8 + e) * 8 + yi * 4;
            float ar = 0.f, ai = 0.f;
            #pragma unroll
            for (int kx = 0; kx < 4; ++kx) {
                float rr = Rs[rb + kx][0], ri = Rs[rb + kx][1];
                ar += rr * Tr[kx] - ri * Ti[kx];
                ai += rr * Ti[kx] + ri * Tr[kx];
            }
            vv[e] = (short)f2bf(sqrtf(ar * ar + ai * ai) * inv);
        }
        Bs[si] = vv;
    }
    __syncthreads();

    int l = tid & 63, w = tid >> 6;
    int wr = w >> 1, wc = w & 1;
    int l15 = l & 15, quad = l >> 4;
    f32x4 acc[2][2] = {};
    int abase = wr * 32 + l15;
    int bbase = wc * 32 + l15;
    #pragma unroll
    for (int s = 0; s < 8; ++s) {
        int kc = s * 4 + quad;
        short8 a0 = As[kc * 64 + abase];
        short8 a1 = As[kc * 64 + abase + 16];
        short8 b0 = Bs[kc * 64 + bbase];
        short8 b1 = Bs[kc * 64 + bbase + 16];
        acc[0][0] = __builtin_amdgcn_mfma_f32_16x16x32_bf16(a0, b0, acc[0][0], 0, 0, 0);
        acc[0][1] = __builtin_amdgcn_mfma_f32_16x16x32_bf16(a0, b1, acc[0][1], 0, 0, 0);
        acc[1][0] = __builtin_amdgcn_mfma_f32_16x16x32_bf16(a1, b0, acc[1][0], 0, 0, 0);
        acc[1][1] = __builtin_amdgcn_mfma_f32_16x16x32_bf16(a1, b1, acc[1][1], 0, 0, 0);
    }
    // C/D layout: col = lane&15, row = quad*4 + reg
    #pragma unroll
    for (int ni = 0; ni < 2; ++ni) {
        #pragma unroll
        for (int r = 0; r < 4; ++r) {
            int o_lo = ot * 64 + wr * 32 + quad * 4 + r;
            float v = fmaxf(acc[0][ni][r] + bias[o_lo], acc[1][ni][r] + bias[o_lo + 16]);
            v = fmaxf(v, __shfl_xor(v, 32, 64));
            if (quad < 2) {
                int p = pt_ * 64 + wc * 32 + ni * 16 + l15;
                int k = ((quad * 4 + r) & 7) * HW + p;
                if (k >= CW) k -= CW;
                if (k >= CW) k -= CW;
                unsigned u = __float_as_uint(v);
                unsigned key = (u & 0x80000000u) ? ~u : (u | 0x80000000u);
                atomicMax(&FQm[k], key);
            }
        }
    }
}

// ---------------- GEMM2: V = Wv*fuse, direct-gather bf16 staging; epilogue = mask ----------------
__global__ __launch_bounds__(256) void k_gemm2(const short8* __restrict__ Wt,
                                               const float* __restrict__ x,
                                               const float* __restrict__ bias,
                                               const unsigned* __restrict__ FQm,
                                               float* __restrict__ out) {
    __shared__ short8 As[2048];          // 32 KB
    __shared__ short8 Bs[2048];          // 32 KB
    int tid = threadIdx.x;
    int pt_ = blockIdx.x, ot = blockIdx.y;
    const short8* wsrc = Wt + ot * 2048;
    #pragma unroll
    for (int i = 0; i < 8; ++i) As[i * 256 + tid] = wsrc[i * 256 + tid];

    int p0 = pt_ * 64;
    // Bs[KC][n][e] = f2bf(x[(KC*8+e)*HW + p0+n]) — per-wave coalesced gather, one barrier
    #pragma unroll
    for (int i = 0; i < 8; ++i) {
        int si = i * 256 + tid;
        int KC = si >> 6, n = si & 63;
        const float* xb = x + (size_t)(KC * 8) * HW + p0 + n;
        short8 v;
        #pragma unroll
        for (int e = 0; e < 8; ++e) v[e] = (short)f2bf(xb[(size_t)e * HW]);
        Bs[si] = v;
    }
    __syncthreads();

    int l = tid & 63, w = tid >> 6;
    int wr = w >> 1, wc = w & 1;
    int l15 = l & 15, quad = l >> 4;
    f32x4 acc[2][2] = {};
    int abase = wr * 32 + l15;
    int bbase = wc * 32 + l15;
    #pragma unroll
    for (int s = 0; s < 8; ++s) {
        int kc = s * 4 + quad;
        short8 a0 = As[kc * 64 + abase];
        short8 a1 = As[kc * 64 + abase + 16];
        short8 b0 = Bs[kc * 64 + bbase];
        short8 b1 = Bs[kc * 64 + bbase + 16];
        acc[0][0] = __builtin_amdgcn_mfma_f32_16x16x32_bf16(a0, b0, acc[0][0], 0, 0, 0);
        acc[0][1] = __builtin_amdgcn_mfma_f32_16x16x32_bf16(a0, b1, acc[0][1], 0, 0, 0);
        acc[1][0] = __builtin_amdgcn_mfma_f32_16x16x32_bf16(a1, b0, acc[1][0], 0, 0, 0);
        acc[1][1] = __builtin_amdgcn_mfma_f32_16x16x32_bf16(a1, b1, acc[1][1], 0, 0, 0);
    }
    #pragma unroll
    for (int mi = 0; mi < 2; ++mi) {
        #pragma unroll
        for (int ni = 0; ni < 2; ++ni) {
            #pragma unroll
            for (int r = 0; r < 4; ++r) {
                int o = ot * 64 + wr * 32 + mi * 16 + quad * 4 + r;
                int p = pt_ * 64 + wc * 32 + ni * 16 + l15;
                int k = ((quad * 4 + r) & 7) * HW + p;
                if (k >= CW) k -= CW;
                if (k >= CW) k -= CW;
                unsigned key = FQm[k];
                unsigned ub = (key & 0x80000000u) ? (key ^ 0x80000000u) : ~key;
                float m = __uint_as_float(ub);
                float v = acc[mi][ni][r] + bias[o];
                out[(size_t)o * HW + p] = v * (1.0f + m);
            }
        }
    }
}

extern "C" void kernel_launch(void* const* d_in, const int* in_sizes, int n_in,
                              void* d_out, int out_size, void* d_ws, size_t ws_size,
                              hipStream_t stream) {
    const float* fuse = (const float*)d_in[0];
    const float* Wq   = (const float*)d_in[1];
    const float* bq   = (const float*)d_in[2];
    // d_in[3]=Wk, d_in[4]=bk dead for B=1 (softmax over batch axis of size 1 == 1)
    const float* Wv   = (const float*)d_in[5];
    const float* bv   = (const float*)d_in[6];
    float* out = (float*)d_out;

    char* ws = (char*)d_ws;
    unsigned* FQm = (unsigned*)(ws);            //  98304 B (zeroed by k_pre)
    float*    Fg  = (float*)(ws + 98304);       //  32768 B
    short8*   Wqt = (short8*)(ws + 131072);     // 131072 B
    short8*   Wvt = (short8*)(ws + 262144);     // 131072 B

    k_pre<<<320, 768, 0, stream>>>(fuse, Wq, Wv, Wqt, Wvt, FQm, Fg);
    k_gemm1<<<dim3(144, 4), 256, 0, stream>>>(Wqt, Fg, bq, FQm);
    k_gemm2<<<dim3(144, 4), 256, 0, stream>>>(Wvt, fuse, bv, FQm, out);
}

// Round 9
// 113.458 us; speedup vs baseline: 1.0584x; 1.0185x over previous
//
#include <hip/hip_runtime.h>
#include <math.h>

#define CCH 256
#define HW  9216
#define CW  24576
#define TWO_PI 6.28318530717958647692f

typedef __attribute__((ext_vector_type(8))) short short8;
typedef __attribute__((ext_vector_type(4))) float f32x4;

__device__ inline unsigned short f2bf(float f) {
    unsigned u = __float_as_uint(f);
    unsigned r = (u + 0x7FFFu + ((u >> 16) & 1u)) >> 16;   // RNE
    return (unsigned short)r;
}

// ---------------- K_pre: fused {per-channel DFT + FQm zero} and {weight conversion} ----------------
// blocks [0,256):  channel c = bid: |x| minmax + 16 DFT coefficients -> Fg; zero FQm slice
// blocks [256,320): Wq/Wv -> bf16 tiles [ot][kc][m]
__global__ __launch_bounds__(768) void k_pre(const float* __restrict__ x,
                                             const float* __restrict__ Wq,
                                             const float* __restrict__ Wv,
                                             short8* __restrict__ Wqt,
                                             short8* __restrict__ Wvt,
                                             unsigned* __restrict__ FQm,
                                             float* __restrict__ Fg) {
    __shared__ float qa[HW];         // 36 KB |x|
    __shared__ float cs[96][2];
    __shared__ float Gp[8][96][5];
    __shared__ float Gs[96][6];
    __shared__ float red[24];
    __shared__ float s_mn, s_ptp;
    int bid = blockIdx.x, t = threadIdx.x;

    if (bid >= 256) {                // weight-conversion blocks
        int widx = bid - 256;        // 0..63
        if (t < 256) {
            const float* src = (widx >= 32) ? Wv : Wq;
            short8* dst = (widx >= 32) ? Wvt : Wqt;
            int cidx = (widx & 31) * 256 + t;             // 0..8191
            int ot = cidx >> 11, kc = (cidx >> 6) & 31, m = cidx & 63;
            const float* s = src + (ot * 64 + m) * 256 + kc * 8;
            short8 v;
            #pragma unroll
            for (int e = 0; e < 8; ++e) v[e] = (short)f2bf(s[e]);
            dst[cidx] = v;
        }
        return;
    }

    int c = bid;
    if (t < 96) FQm[c * 96 + t] = 0u;   // zero FQm (24576 words over 256 blocks)
    const float* xp = x + c * HW;
    if (t < 96) { float a = TWO_PI * (float)t / 96.0f; cs[t][0] = cosf(a); cs[t][1] = sinf(a); }
    float lo = 1e30f, hi = 0.f;
    #pragma unroll
    for (int i = 0; i < 12; ++i) {
        float a = fabsf(xp[t + i * 768]);
        qa[t + i * 768] = a;
        lo = fminf(lo, a);
        hi = fmaxf(hi, a);
    }
    #pragma unroll
    for (int d = 32; d; d >>= 1) {
        lo = fminf(lo, __shfl_xor(lo, d, 64));
        hi = fmaxf(hi, __shfl_xor(hi, d, 64));
    }
    if ((t & 63) == 0) { red[t >> 6] = lo; red[12 + (t >> 6)] = hi; }
    __syncthreads();
    if (t == 0) {
        lo = red[0]; hi = red[12];
        #pragma unroll
        for (int i = 1; i < 12; ++i) { lo = fminf(lo, red[i]); hi = fmaxf(hi, red[12 + i]); }
        s_mn = lo; s_ptp = hi - lo;
    }
    __syncthreads();
    float mn = s_mn, ptp = s_ptp;

    // Phase A: thread (xx = t%96, h = t/96) sums 12 rows of the column DFT from LDS
    {
        int xx = t % 96, h = t / 96;
        float g0r = 0, g0i = 0, g1r = 0, g1i = 0, g2 = 0;
        for (int y = h * 12; y < h * 12 + 12; ++y) {
            float q = floorf(255.0f * (qa[y * 96 + xx] - mn) / ptp);
            float c1 = cs[y][0], s1 = cs[y][1];
            float c2 = c1 * c1 - s1 * s1, s2 = 2.0f * c1 * s1;
            g0r += q * c2; g0i += q * s2;   // k=-2: e^{+2iθ}
            g1r += q * c1; g1i += q * s1;   // k=-1: e^{+iθ}
            g2  += q;                       // k=0
        }
        Gp[h][xx][0] = g0r; Gp[h][xx][1] = g0i;
        Gp[h][xx][2] = g1r; Gp[h][xx][3] = g1i;
        Gp[h][xx][4] = g2;
    }
    __syncthreads();
    if (t < 96) {
        #pragma unroll
        for (int j = 0; j < 5; ++j) {
            float s = 0.f;
            #pragma unroll
            for (int h = 0; h < 8; ++h) s += Gp[h][t][j];
            Gs[t][j] = s;
        }
        Gs[t][5] = 0.f;
    }
    __syncthreads();
    if (t < 64) {
        int coef = t >> 2, qq = t & 3;
        int ky = coef >> 2, kx = coef & 3;
        float fr = 0, fi = 0;
        for (int xx = qq * 24; xx < qq * 24 + 24; ++xx) {
            float c1 = cs[xx][0], s1 = cs[xx][1];
            float er, ei;
            if (kx == 0)      { er = c1 * c1 - s1 * s1; ei = 2.0f * c1 * s1; }
            else if (kx == 1) { er = c1; ei = s1; }
            else if (kx == 2) { er = 1.f; ei = 0.f; }
            else              { er = c1; ei = -s1; }
            float gr, gi;
            if (ky == 0)      { gr = Gs[xx][0]; gi = Gs[xx][1]; }
            else if (ky == 1) { gr = Gs[xx][2]; gi = Gs[xx][3]; }
            else if (ky == 2) { gr = Gs[xx][4]; gi = 0.f; }
            else              { gr = Gs[xx][2]; gi = -Gs[xx][3]; }
            fr += gr * er - gi * ei;
            fi += gr * ei + gi * er;
        }
        fr += __shfl_xor(fr, 1, 64); fr += __shfl_xor(fr, 2, 64);
        fi += __shfl_xor(fi, 1, 64); fi += __shfl_xor(fi, 2, 64);
        if (qq == 0) {
            Fg[c * 32 + 2 * coef]     = fr;
            Fg[c * 32 + 2 * coef + 1] = fi;
        }
    }
}

// ---------------- K_gemmQV: grid (144, 8). y<4: Q-GEMM (synth B, colmax epilogue).
//                  y>=4: V-GEMM (gather B, raw V -> out). Both 64x64, K=256 one-shot.
__global__ __launch_bounds__(256) void k_gemmQV(const short8* __restrict__ Wqt,
                                                const short8* __restrict__ Wvt,
                                                const float* __restrict__ Fg,
                                                const float* __restrict__ bq,
                                                const float* __restrict__ bv,
                                                const float* __restrict__ x,
                                                unsigned* __restrict__ FQm,
                                                float* __restrict__ out) {
    __shared__ short8 As[2048];     // 32 KB [kc][m]
    __shared__ short8 Bs[2048];     // 32 KB [kc][n]
    __shared__ float Rs[2048][2];   // 16 KB (Q-path only)
    int tid = threadIdx.x;
    int pt_ = blockIdx.x;
    bool isQ = blockIdx.y < 4;
    int ot = isQ ? blockIdx.y : blockIdx.y - 4;
    const short8* wsrc = (isQ ? Wqt : Wvt) + ot * 2048;
    #pragma unroll
    for (int i = 0; i < 8; ++i) As[i * 256 + tid] = wsrc[i * 256 + tid];

    int p0 = pt_ * 64;
    if (isQ) {
        int y0 = p0 / 96;
        // R[c][yi][kx] = sum_ky F[c][ky][kx] * U[ky](y0+yi)
        {
            int yi = (tid >> 2) & 1, kx = tid & 3, cb = tid >> 3;
            float ay = TWO_PI * (float)(y0 + yi) / 96.0f;
            float cyv = cosf(ay), syv = sinf(ay);
            float cy2 = cyv * cyv - syv * syv, sy2 = 2.f * cyv * syv;
            float Ur[4] = { cy2, cyv, 1.f, cyv };
            float Ui[4] = { -sy2, -syv, 0.f, syv };
            #pragma unroll
            for (int i = 0; i < 8; ++i) {
                int cc = cb + i * 32;
                float rr = 0.f, ri = 0.f;
                #pragma unroll
                for (int ky = 0; ky < 4; ++ky) {
                    float fr = Fg[cc * 32 + 2 * (ky * 4 + kx)];
                    float fi = Fg[cc * 32 + 2 * (ky * 4 + kx) + 1];
                    rr += fr * Ur[ky] - fi * Ui[ky];
                    ri += fr * Ui[ky] + fi * Ur[ky];
                }
                Rs[cc * 8 + yi * 4 + kx][0] = rr;
                Rs[cc * 8 + yi * 4 + kx][1] = ri;
            }
        }
        __syncthreads();
        // Bs[kc][n] = f2bf(|sum_kx R[c][yi(n)][kx] * T[kx](x(n))| / 9216)
        const float inv = 1.0f / 9216.0f;
        #pragma unroll
        for (int i = 0; i < 8; ++i) {
            int si = i * 256 + tid;
            int kcg = si >> 6, n = si & 63;
            int p = p0 + n;
            int y = p / 96, xx = p - y * 96;
            int yi = y - y0;
            float axv = TWO_PI * (float)xx / 96.0f;
            float cxv = cosf(axv), sxv = sinf(axv);
            float cx2 = cxv * cxv - sxv * sxv, sx2 = 2.f * cxv * sxv;
            float Tr[4] = { cx2, cxv, 1.f, cxv };
            float Ti[4] = { -sx2, -sxv, 0.f, sxv };
            short8 vv;
            #pragma unroll
            for (int e = 0; e < 8; ++e) {
                int rb = (kcg * 8 + e) * 8 + yi * 4;
                float ar = 0.f, ai = 0.f;
                #pragma unroll
                for (int kx = 0; kx < 4; ++kx) {
                    float rr = Rs[rb + kx][0], ri = Rs[rb + kx][1];
                    ar += rr * Tr[kx] - ri * Ti[kx];
                    ai += rr * Ti[kx] + ri * Tr[kx];
                }
                vv[e] = (short)f2bf(sqrtf(ar * ar + ai * ai) * inv);
            }
            Bs[si] = vv;
        }
    } else {
        // Bs[KC][n][e] = f2bf(x[(KC*8+e)*HW + p0+n]) — per-wave coalesced gather
        #pragma unroll
        for (int i = 0; i < 8; ++i) {
            int si = i * 256 + tid;
            int KC = si >> 6, n = si & 63;
            const float* xb = x + (size_t)(KC * 8) * HW + p0 + n;
            short8 v;
            #pragma unroll
            for (int e = 0; e < 8; ++e) v[e] = (short)f2bf(xb[(size_t)e * HW]);
            Bs[si] = v;
        }
    }
    __syncthreads();

    int l = tid & 63, w = tid >> 6;
    int wr = w >> 1, wc = w & 1;
    int l15 = l & 15, quad = l >> 4;
    f32x4 acc[2][2] = {};
    int abase = wr * 32 + l15;
    int bbase = wc * 32 + l15;
    #pragma unroll
    for (int s = 0; s < 8; ++s) {
        int kc = s * 4 + quad;
        short8 a0 = As[kc * 64 + abase];
        short8 a1 = As[kc * 64 + abase + 16];
        short8 b0 = Bs[kc * 64 + bbase];
        short8 b1 = Bs[kc * 64 + bbase + 16];
        acc[0][0] = __builtin_amdgcn_mfma_f32_16x16x32_bf16(a0, b0, acc[0][0], 0, 0, 0);
        acc[0][1] = __builtin_amdgcn_mfma_f32_16x16x32_bf16(a0, b1, acc[0][1], 0, 0, 0);
        acc[1][0] = __builtin_amdgcn_mfma_f32_16x16x32_bf16(a1, b0, acc[1][0], 0, 0, 0);
        acc[1][1] = __builtin_amdgcn_mfma_f32_16x16x32_bf16(a1, b1, acc[1][1], 0, 0, 0);
    }

    // C/D layout: col = lane&15, row = quad*4 + reg
    if (isQ) {
        #pragma unroll
        for (int ni = 0; ni < 2; ++ni) {
            #pragma unroll
            for (int r = 0; r < 4; ++r) {
                int o_lo = ot * 64 + wr * 32 + quad * 4 + r;
                float v = fmaxf(acc[0][ni][r] + bq[o_lo], acc[1][ni][r] + bq[o_lo + 16]);
                v = fmaxf(v, __shfl_xor(v, 32, 64));
                if (quad < 2) {
                    int p = pt_ * 64 + wc * 32 + ni * 16 + l15;
                    int k = ((quad * 4 + r) & 7) * HW + p;
                    if (k >= CW) k -= CW;
                    if (k >= CW) k -= CW;
                    unsigned u = __float_as_uint(v);
                    unsigned key = (u & 0x80000000u) ? ~u : (u | 0x80000000u);
                    atomicMax(&FQm[k], key);
                }
            }
        }
    } else {
        #pragma unroll
        for (int mi = 0; mi < 2; ++mi) {
            #pragma unroll
            for (int ni = 0; ni < 2; ++ni) {
                #pragma unroll
                for (int r = 0; r < 4; ++r) {
                    int o = ot * 64 + wr * 32 + mi * 16 + quad * 4 + r;
                    int p = pt_ * 64 + wc * 32 + ni * 16 + l15;
                    out[(size_t)o * HW + p] = acc[mi][ni][r] + bv[o];   // raw V
                }
            }
        }
    }
}

// ---------------- K_mask: out *= (1 + decode(FQm[k])) — pure streaming ----------------
__device__ inline float mdecode(unsigned key) {
    unsigned ub = (key & 0x80000000u) ? (key ^ 0x80000000u) : ~key;
    return __uint_as_float(ub);
}
__global__ __launch_bounds__(256) void k_mask(float* __restrict__ out,
                                              const unsigned* __restrict__ FQm) {
    int i = (blockIdx.x * 256 + threadIdx.x) * 8;
    int o = i / HW;                       // 9216 | i-run per channel, 8-aligned
    int p = i - o * HW;
    int k = (o & 7) * HW + p;
    if (k >= CW) k -= CW;
    if (k >= CW) k -= CW;                 // max 73727 -> two subtractions suffice
    // k ≡ p (mod 8), CW % 8 == 0 -> the 8-run never wraps mod CW
    float4 v0 = *(const float4*)(out + i);
    float4 v1 = *(const float4*)(out + i + 4);
    uint4 k0 = *(const uint4*)(FQm + k);
    uint4 k1 = *(const uint4*)(FQm + k + 4);
    v0.x *= 1.0f + mdecode(k0.x); v0.y *= 1.0f + mdecode(k0.y);
    v0.z *= 1.0f + mdecode(k0.z); v0.w *= 1.0f + mdecode(k0.w);
    v1.x *= 1.0f + mdecode(k1.x); v1.y *= 1.0f + mdecode(k1.y);
    v1.z *= 1.0f + mdecode(k1.z); v1.w *= 1.0f + mdecode(k1.w);
    *(float4*)(out + i)     = v0;
    *(float4*)(out + i + 4) = v1;
}

extern "C" void kernel_launch(void* const* d_in, const int* in_sizes, int n_in,
                              void* d_out, int out_size, void* d_ws, size_t ws_size,
                              hipStream_t stream) {
    const float* fuse = (const float*)d_in[0];
    const float* Wq   = (const float*)d_in[1];
    const float* bq   = (const float*)d_in[2];
    // d_in[3]=Wk, d_in[4]=bk dead for B=1 (softmax over batch axis of size 1 == 1)
    const float* Wv   = (const float*)d_in[5];
    const float* bv   = (const float*)d_in[6];
    float* out = (float*)d_out;

    char* ws = (char*)d_ws;
    unsigned* FQm = (unsigned*)(ws);            //  98304 B (zeroed by k_pre)
    float*    Fg  = (float*)(ws + 98304);       //  32768 B
    short8*   Wqt = (short8*)(ws + 131072);     // 131072 B
    short8*   Wvt = (short8*)(ws + 262144);     // 131072 B

    k_pre<<<320, 768, 0, stream>>>(fuse, Wq, Wv, Wqt, Wvt, FQm, Fg);
    k_gemmQV<<<dim3(144, 8), 256, 0, stream>>>(Wqt, Wvt, Fg, bq, bv, fuse, FQm, out);
    k_mask<<<1152, 256, 0, stream>>>(out, FQm);
}